// Round 21
// baseline (336.157 us; speedup 1.0000x reference)
//
#include <hip/hip_runtime.h>

#define NB 2
#define NS 4096
#define ND 1152
#define NH 16
#define HD 72
#define HP 80            // q/k padded head dim (cols 72..79 zero)
#define VP 96            // v_t rows (72=ones, 73..95 zero)
// 72^-0.5 * log2(e): attention computed in exp2 domain
#define QSCALE (0.11785113019775793f * 1.4426950408889634f)

typedef float f32x4 __attribute__((ext_vector_type(4)));
typedef float f32x16 __attribute__((ext_vector_type(16)));
typedef __bf16 bf16x8 __attribute__((ext_vector_type(8)));
typedef unsigned short u16x8 __attribute__((ext_vector_type(8)));
typedef unsigned short u16x4 __attribute__((ext_vector_type(4)));
typedef unsigned int u32x4 __attribute__((ext_vector_type(4)));

__device__ __forceinline__ unsigned short f2bf(float f) {
  return __builtin_bit_cast(unsigned short, (__bf16)f);  // v_cvt RNE
}
__device__ __forceinline__ bf16x8 asbf(u16x8 u) {
  return __builtin_bit_cast(bf16x8, u);
}
__device__ __forceinline__ unsigned cvtpk(float lo, float hi) {
  unsigned d;
  asm("v_cvt_pk_bf16_f32 %0, %1, %2" : "=v"(d) : "v"(lo), "v"(hi));
  return d;
}
__device__ __forceinline__ void lane32swap(unsigned &x, unsigned &y) {
  asm volatile("v_permlane32_swap_b32 %0, %1" : "+v"(x), "+v"(y));
}
// bare hardware exp2 with COMPILER-managed VALU->TRANS hazards (R15's raw
// inline-asm version broke correctness; the builtin is the safe form).
#if __has_builtin(__builtin_amdgcn_exp2f)
#define EXP2(x) __builtin_amdgcn_exp2f(x)
#else
#define EXP2(x) exp2f(x)
#endif
// async global->LDS, 16B per lane; lds dst = wave-uniform base + lane*16
__device__ __forceinline__ void gll16(const void* g, void* l) {
  __builtin_amdgcn_global_load_lds(
      (__attribute__((address_space(1))) void*)(unsigned long long)g,
      (__attribute__((address_space(3))) void*)l, 16, 0, 0);
}

// ---------------------------------------------------------------------------
// fused pre-pass: fp32->bf16 for x + qw/kw/vw (blocks < 6552) AND pads
// (blocks >= 6552): q80/k80 cols 72..79 zero; v_t rows 72..95 (72 = ones).
// ---------------------------------------------------------------------------
__global__ __launch_bounds__(256) void cvt_pad(
    const float* __restrict__ x,
    const float* __restrict__ qw, const float* __restrict__ kw,
    const float* __restrict__ vw,
    unsigned short* __restrict__ xb, unsigned short* __restrict__ wb,
    unsigned short* __restrict__ q80, unsigned short* __restrict__ k80,
    unsigned short* __restrict__ vt) {
  if (blockIdx.x < 6552) {
    const size_t NX = (size_t)8192 * ND;      // 9437184
    const size_t NW = (size_t)ND * ND;        // 1327104
    size_t i = ((size_t)blockIdx.x * 256 + threadIdx.x) * 8;
    const float* s; unsigned short* d; size_t off;
    if (i < NX)            { s = x;  d = xb;          off = i; }
    else if (i < NX + NW)  { s = qw; d = wb;          off = i - NX; }
    else if (i < NX + 2*NW){ s = kw; d = wb + NW;     off = i - NX - NW; }
    else                   { s = vw; d = wb + 2 * NW; off = i - NX - 2 * NW; }
    f32x4 a = *(const f32x4*)(s + off);
    f32x4 b = *(const f32x4*)(s + off + 4);
    u16x8 o;
#pragma unroll
    for (int j = 0; j < 4; ++j) { o[j] = f2bf(a[j]); o[j + 4] = f2bf(b[j]); }
    *(u16x8*)(d + off) = o;
  } else {
    int i = (blockIdx.x - 6552) * 256 + threadIdx.x;
    u16x8 z = {};
    if (i < 131072) {
      *(u16x8*)(q80 + (size_t)i * HP + HD) = z;
    } else if (i < 262144) {
      *(u16x8*)(k80 + (size_t)(i - 131072) * HP + HD) = z;
    } else {
      int j = i - 262144;               // 0..393215
      int bh = j / 12288;               // 24 rows * 512 chunks per bh
      int r = j % 12288;
      int row = 72 + r / 512;
      int col = (r % 512) * 8;
      u16x8 v = z;
      if (row == HD) {
#pragma unroll
        for (int j8 = 0; j8 < 8; ++j8) v[j8] = 0x3F80;   // bf16 1.0
      }
      *(u16x8*)(vt + ((size_t)bh * VP + row) * NS + col) = v;
    }
  }
}

// ---------------------------------------------------------------------------
// Q/K projection (m97 gll structure, branchless inner loop): z picks q|k.
// C = xb . wb[z]^T + bias; 128x128 tile, BK=64, LDS [128][64] linear,
// both operands via global_load_lds width-16. Epilogue -> q80(xQSCALE)/k80.
// ---------------------------------------------------------------------------
__global__ __launch_bounds__(256) void qk_gemm(
    const unsigned short* __restrict__ xb, const unsigned short* __restrict__ wb,
    const float* __restrict__ qbias, const float* __restrict__ kbias,
    unsigned short* __restrict__ qp, unsigned short* __restrict__ kp)
{
  const int mb = blockIdx.x * 128;
  const int nb = blockIdx.y * 128;
  const int proj = blockIdx.z;
  const unsigned short* w = wb + (size_t)proj * (ND * ND);
  const float* bias = proj == 0 ? qbias : kbias;

  __shared__ __align__(16) unsigned short la[128 * 64];
  __shared__ __align__(16) unsigned short lb[128 * 64];

  const int t = threadIdx.x;
  const int lane = t & 63;
  const int wid = t >> 6;
  const int mo = (wid >> 1) * 64, no = (wid & 1) * 64;
  const int l15 = lane & 15, l4 = lane >> 4;

  const unsigned short* ga = xb + (size_t)(mb + wid * 32 + (lane >> 3)) * ND + (lane & 7) * 8;
  const unsigned short* gb = w  + (size_t)(nb + wid * 32 + (lane >> 3)) * ND + (lane & 7) * 8;

  f32x4 acc[4][4] = {};

  for (int kt = 0; kt < ND / 64; ++kt) {
    const int k0 = kt * 64;
    __syncthreads();
#pragma unroll
    for (int j = 0; j < 4; ++j) {
      gll16(ga + (size_t)j * 8 * ND + k0, &la[(wid * 4 + j) * 512]);
      gll16(gb + (size_t)j * 8 * ND + k0, &lb[(wid * 4 + j) * 512]);
    }
    __syncthreads();
#pragma unroll
    for (int ks = 0; ks < 2; ++ks) {
      bf16x8 af[4], bfr[4];
#pragma unroll
      for (int mt = 0; mt < 4; ++mt)
        af[mt] = asbf(*(const u16x8*)(&la[(mo + mt * 16 + l15) * 64 + ks * 32 + l4 * 8]));
#pragma unroll
      for (int nt = 0; nt < 4; ++nt)
        bfr[nt] = asbf(*(const u16x8*)(&lb[(no + nt * 16 + l15) * 64 + ks * 32 + l4 * 8]));
#pragma unroll
      for (int mt = 0; mt < 4; ++mt)
#pragma unroll
        for (int nt = 0; nt < 4; ++nt)
          acc[mt][nt] = __builtin_amdgcn_mfma_f32_16x16x32_bf16(af[mt], bfr[nt], acc[mt][nt], 0, 0, 0);
    }
  }

#pragma unroll
  for (int mt = 0; mt < 4; ++mt) {
#pragma unroll
    for (int nt = 0; nt < 4; ++nt) {
      const int n = nb + no + nt * 16 + l15;
      const float bval = bias[n];
      const int h = n / HD, hd = n % HD;
#pragma unroll
      for (int r = 0; r < 4; ++r) {
        const int m = mb + mo + mt * 16 + l4 * 4 + r;
        const int b = m >> 12, sl = m & (NS - 1);
        const int bh = b * NH + h;
        float v = acc[mt][nt][r] + bval;
        if (proj == 0)
          qp[((size_t)bh * NS + sl) * HP + hd] = f2bf(v * QSCALE);
        else
          kp[((size_t)bh * NS + sl) * HP + hd] = f2bf(v);
      }
    }
  }
}

// ---------------------------------------------------------------------------
// V projection (m97 gll structure, always-swapped MFMA -> C^T): v_t stores
// contiguous along s.
// ---------------------------------------------------------------------------
__global__ __launch_bounds__(256) void v_gemm(
    const unsigned short* __restrict__ xb, const unsigned short* __restrict__ wv,
    const float* __restrict__ vb, unsigned short* __restrict__ vt)
{
  const int mb = blockIdx.x * 128;
  const int nb = blockIdx.y * 128;

  __shared__ __align__(16) unsigned short la[128 * 64];
  __shared__ __align__(16) unsigned short lb[128 * 64];

  const int t = threadIdx.x;
  const int lane = t & 63;
  const int wid = t >> 6;
  const int mo = (wid >> 1) * 64, no = (wid & 1) * 64;
  const int l15 = lane & 15, l4 = lane >> 4;

  const unsigned short* ga = xb + (size_t)(mb + wid * 32 + (lane >> 3)) * ND + (lane & 7) * 8;
  const unsigned short* gb = wv + (size_t)(nb + wid * 32 + (lane >> 3)) * ND + (lane & 7) * 8;

  f32x4 acc[4][4] = {};

  for (int kt = 0; kt < ND / 64; ++kt) {
    const int k0 = kt * 64;
    __syncthreads();
#pragma unroll
    for (int j = 0; j < 4; ++j) {
      gll16(ga + (size_t)j * 8 * ND + k0, &la[(wid * 4 + j) * 512]);
      gll16(gb + (size_t)j * 8 * ND + k0, &lb[(wid * 4 + j) * 512]);
    }
    __syncthreads();
#pragma unroll
    for (int ks = 0; ks < 2; ++ks) {
      bf16x8 af[4], bfr[4];
#pragma unroll
      for (int mt = 0; mt < 4; ++mt)
        af[mt] = asbf(*(const u16x8*)(&la[(mo + mt * 16 + l15) * 64 + ks * 32 + l4 * 8]));
#pragma unroll
      for (int nt = 0; nt < 4; ++nt)
        bfr[nt] = asbf(*(const u16x8*)(&lb[(no + nt * 16 + l15) * 64 + ks * 32 + l4 * 8]));
#pragma unroll
      for (int mt = 0; mt < 4; ++mt)
#pragma unroll
        for (int nt = 0; nt < 4; ++nt)
          acc[mt][nt] = __builtin_amdgcn_mfma_f32_16x16x32_bf16(bfr[nt], af[mt], acc[mt][nt], 0, 0, 0);
    }
  }

  // acc = C^T: col(l15)=m, row(l4*4+r)=n -> stores contiguous along s
#pragma unroll
  for (int mt = 0; mt < 4; ++mt) {
    const int m = mb + mo + mt * 16 + l15;
    const int b = m >> 12, sl = m & (NS - 1);
#pragma unroll
    for (int nt = 0; nt < 4; ++nt) {
#pragma unroll
      for (int r = 0; r < 4; ++r) {
        const int n = nb + no + nt * 16 + l4 * 4 + r;
        const int h = n / HD, hd = n % HD;
        vt[(((size_t)(b * NH + h)) * VP + hd) * NS + sl] =
            f2bf(acc[mt][nt][r] + vb[n]);
      }
    }
  }
}

// ---------------------------------------------------------------------------
// exp2 + pack + PV for one 32-q group (hardware exp2 via builtin; o[3] in regs)
// ---------------------------------------------------------------------------
__device__ __forceinline__ void softmax_pv(f32x16 s, const unsigned short* cur,
                                           int mt, int lane, f32x16 o[3]) {
#pragma unroll
  for (int i = 0; i < 16; ++i) s[i] = EXP2(s[i]);
  unsigned dk[8];
#pragma unroll
  for (int r2 = 0; r2 < 4; ++r2) {
    dk[2 * r2]     = cvtpk(s[4 * r2],     s[4 * r2 + 1]);
    dk[2 * r2 + 1] = cvtpk(s[4 * r2 + 2], s[4 * r2 + 3]);
  }
#pragma unroll
  for (int a = 0; a < 2; ++a) {
    unsigned x0 = dk[4 * a + 0], y0 = dk[4 * a + 2];
    unsigned x1 = dk[4 * a + 1], y1 = dk[4 * a + 3];
    lane32swap(x0, y0);
    lane32swap(x1, y1);
    u32x4 wd = {x0, x1, y0, y1};
    bf16x8 pf = __builtin_bit_cast(bf16x8, wd);
    const int ks2 = mt * 2 + a;
    __builtin_amdgcn_s_setprio(1);
#pragma unroll
    for (int hdt = 0; hdt < 3; ++hdt) {
      bf16x8 vf = asbf(*(const u16x8*)(&cur[(640 + (hdt * 4 + ks2) * 64 + lane) * 8]));
      o[hdt] = __builtin_amdgcn_mfma_f32_32x32x16_bf16(vf, pf, o[hdt], 0, 0, 0);
    }
    __builtin_amdgcn_s_setprio(0);
  }
}

// ---------------------------------------------------------------------------
// Flash attention (R20 + wave-staggered phases) + piggyback ow->bf16 cvt.
// Odd waves process k-sub-tiles in reverse order (mt = mti ^ (wv&1)) so at
// any instant half the waves are in the MFMA phase while half run exp/pack
// VALU -> MFMA and VALU/TRANS pipes overlap instead of phase-aligning
// (R20 counters: MfmaUtil 55 + VALUBusy 41 = 96% => serial pipes).
// ---------------------------------------------------------------------------
__global__ __launch_bounds__(512, 4) void attn_fwd(
    const unsigned short* __restrict__ qp,
    const unsigned short* __restrict__ kp,
    const unsigned short* __restrict__ vt,
    unsigned short* __restrict__ ao,
    const float* __restrict__ ow, unsigned short* __restrict__ owb)
{
  if (blockIdx.x >= 512) {             // o_w converter blocks
    const int tid = (blockIdx.x - 512) * 512 + threadIdx.x;  // 0..8191
    for (size_t c = tid; c < (size_t)ND * ND / 8; c += 8192) {
      size_t off = c * 8;
      f32x4 a = *(const f32x4*)(ow + off);
      f32x4 b = *(const f32x4*)(ow + off + 4);
      u16x8 o;
#pragma unroll
      for (int j = 0; j < 4; ++j) { o[j] = f2bf(a[j]); o[j + 4] = f2bf(b[j]); }
      *(u16x8*)(owb + off) = o;
    }
    return;
  }

  const int d = blockIdx.x;            // 512 attn blocks, 2 per CU
  const int qt = (d >> 3) & 15;
  const int bh = (d & 7) + 8 * (d >> 7);
  const int b = bh >> 4, h = bh & 15;
  const int qs0 = qt * 256;

  // two buffers of 1408 16B-chunks: K chunks 0..639, V chunks 640..1407
  __shared__ __align__(16) unsigned short sm[2 * 1408 * 8];

  const int t = threadIdx.x;
  const int wv = t >> 6;
  const int lane = t & 63;
  const int q = lane & 31;
  const int hh = lane >> 5;

  // Q B-frags: lane holds Q[q][ks*16 + hh*8 + j]
  bf16x8 qf[5];
  {
    const unsigned short* qrow =
        qp + ((size_t)bh * NS + qs0 + wv * 32 + q) * HP + hh * 8;
#pragma unroll
    for (int ks = 0; ks < 5; ++ks)
      qf[ks] = asbf(*(const u16x8*)(qrow + ks * 16));
  }

  // staging: 22 chunk-groups of 64; wave wv handles g = wv, wv+8, wv+16(wv<6).
  // g<10: K group (mt=g/5, ks=g%5); g>=10: V group f=g-10 (hdt=f>>2, ks2=f&3).
  const unsigned short* kb0 = kp + (size_t)bh * NS * HP;
  const unsigned short* vb0 = vt + (size_t)bh * VP * NS;
  const unsigned short* gp[3];
  int stp[3], goff[3];
  const bool has2 = wv < 6;
#pragma unroll
  for (int j = 0; j < 3; ++j) {
    int g = wv + 8 * j;
    if (g > 21) g = 21;                // inert clamp for waves 6,7 j=2
    if (g < 10) {
      gp[j] = kb0 + ((g / 5) * 32 + (lane & 31)) * HP + (g % 5) * 16 + (lane >> 5) * 8;
      stp[j] = 64 * HP;
    } else {
      const int f = g - 10;
      gp[j] = vb0 + (size_t)((f >> 2) * 32 + (lane & 31)) * NS + (f & 3) * 16 + (lane >> 5) * 8;
      stp[j] = 64;
    }
    goff[j] = g * 512;
  }

  const int mtx = wv & 1;              // phase stagger: odd waves reverse mt

  f32x16 o[3] = {};   // O^T: col q, row hd = hdt*32+(reg&3)+8*(reg>>2)+4*hh

  // prologue: stage tile 0 into buffer 0
  gll16(gp[0], sm + goff[0]); gp[0] += stp[0];
  gll16(gp[1], sm + goff[1]); gp[1] += stp[1];
  if (has2) { gll16(gp[2], sm + goff[2]); gp[2] += stp[2]; }
  __syncthreads();

  for (int it = 0; it < NS / 64; ++it) {
    unsigned short* cur = sm + (it & 1) * 11264;
    unsigned short* nxt = sm + ((it + 1) & 1) * 11264;
    if (it < NS / 64 - 1) {            // issue next tile; drains at the barrier
      gll16(gp[0], nxt + goff[0]); gp[0] += stp[0];
      gll16(gp[1], nxt + goff[1]); gp[1] += stp[1];
      if (has2) { gll16(gp[2], nxt + goff[2]); gp[2] += stp[2]; }
    }

#pragma unroll
    for (int mti = 0; mti < 2; ++mti) {
      const int mt = mti ^ mtx;        // wave-uniform runtime sub-tile index
      // S^T tile [32k x 32q], contraction over hd 0..79
      f32x16 s = {};
      __builtin_amdgcn_s_setprio(1);
#pragma unroll
      for (int ks = 0; ks < 5; ++ks) {
        bf16x8 kf = asbf(*(const u16x8*)(&cur[((mt * 5 + ks) * 64 + lane) * 8]));
        s = __builtin_amdgcn_mfma_f32_32x32x16_bf16(kf, qf[ks], s, 0, 0, 0);
      }
      __builtin_amdgcn_s_setprio(0);
      softmax_pv(s, cur, mt, lane, o);
    }
    __syncthreads();                   // drains gll(t+1); all waves done w/ cur
  }

  // epilogue: denom = O row 72 (o[2] reg 4, hh=0 lanes)
  const float l_tot = __shfl(o[2][4], q);
  const float inv = 1.0f / l_tot;
  const int srow = qs0 + wv * 32 + q;
  unsigned short* ob = ao + ((size_t)b * NS + srow) * ND + h * HD;
#pragma unroll
  for (int hdt = 0; hdt < 3; ++hdt)
#pragma unroll
    for (int r2 = 0; r2 < 4; ++r2) {
      const int hd0 = hdt * 32 + r2 * 8 + hh * 4;
      if (hd0 < HD) {
        u16x4 ov;
#pragma unroll
        for (int r0 = 0; r0 < 4; ++r0) ov[r0] = f2bf(o[hdt][r2 * 4 + r0] * inv);
        *(u16x4*)(ob + hd0) = ov;
      }
    }
}

// ---------------------------------------------------------------------------
// O projection (qk_gemm gll structure, both operands bf16):
// out[8192,1152] fp32 = attn_o(bf16) . ow_bf16^T + o_b
// ---------------------------------------------------------------------------
__global__ __launch_bounds__(256) void oproj_gemm(
    const unsigned short* __restrict__ a,
    const unsigned short* __restrict__ wbf, const float* __restrict__ bias,
    float* __restrict__ out)
{
  const int mb = blockIdx.x * 128;
  const int nb = blockIdx.y * 128;

  __shared__ __align__(16) unsigned short la[128 * 64];
  __shared__ __align__(16) unsigned short lb[128 * 64];

  const int t = threadIdx.x;
  const int lane = t & 63;
  const int wid = t >> 6;
  const int mo = (wid >> 1) * 64, no = (wid & 1) * 64;
  const int l15 = lane & 15, l4 = lane >> 4;

  const unsigned short* ga = a   + (size_t)(mb + wid * 32 + (lane >> 3)) * ND + (lane & 7) * 8;
  const unsigned short* gb = wbf + (size_t)(nb + wid * 32 + (lane >> 3)) * ND + (lane & 7) * 8;

  f32x4 acc[4][4] = {};

  for (int kt = 0; kt < ND / 64; ++kt) {
    const int k0 = kt * 64;
    __syncthreads();
#pragma unroll
    for (int j = 0; j < 4; ++j) {
      gll16(ga + (size_t)j * 8 * ND + k0, &la[(wid * 4 + j) * 512]);
      gll16(gb + (size_t)j * 8 * ND + k0, &lb[(wid * 4 + j) * 512]);
    }
    __syncthreads();
#pragma unroll
    for (int ks = 0; ks < 2; ++ks) {
      bf16x8 af[4], bfr[4];
#pragma unroll
      for (int mt = 0; mt < 4; ++mt)
        af[mt] = asbf(*(const u16x8*)(&la[(mo + mt * 16 + l15) * 64 + ks * 32 + l4 * 8]));
#pragma unroll
      for (int nt = 0; nt < 4; ++nt)
        bfr[nt] = asbf(*(const u16x8*)(&lb[(no + nt * 16 + l15) * 64 + ks * 32 + l4 * 8]));
#pragma unroll
      for (int mt = 0; mt < 4; ++mt)
#pragma unroll
        for (int nt = 0; nt < 4; ++nt)
          acc[mt][nt] = __builtin_amdgcn_mfma_f32_16x16x32_bf16(af[mt], bfr[nt], acc[mt][nt], 0, 0, 0);
    }
  }

#pragma unroll
  for (int mt = 0; mt < 4; ++mt)
#pragma unroll
    for (int nt = 0; nt < 4; ++nt) {
      const int n = nb + no + nt * 16 + l15;
      const float bval = bias[n];
#pragma unroll
      for (int r = 0; r < 4; ++r) {
        const int m = mb + mo + mt * 16 + l4 * 4 + r;
        out[(size_t)m * ND + n] = acc[mt][nt][r] + bval;
      }
    }
}

// ---------------------------------------------------------------------------
extern "C" void kernel_launch(void* const* d_in, const int* in_sizes, int n_in,
                              void* d_out, int out_size, void* d_ws, size_t ws_size,
                              hipStream_t stream) {
  const float* x  = (const float*)d_in[0];
  const float* qw = (const float*)d_in[1];
  const float* qb = (const float*)d_in[2];
  const float* kw = (const float*)d_in[3];
  const float* kb = (const float*)d_in[4];
  const float* vw = (const float*)d_in[5];
  const float* vb = (const float*)d_in[6];
  const float* ow = (const float*)d_in[7];
  const float* ob = (const float*)d_in[8];
  float* out = (float*)d_out;

  // ws layout (bytes), total 93,945,856 (== R7's proven footprint):
  //   q80    [2,16,4096,80] bf16 @ 0           (20,971,520)
  //   k80    [2,16,4096,80] bf16 @ 20,971,520  (20,971,520)
  //   v_t    [2,16,96,4096] bf16 @ 41,943,040  (25,165,824)
  //   xb/ao  [8192,1152]    bf16 @ 67,108,864  (18,874,368)  xb dies before ao
  //   wqkv   3x[1152,1152]  bf16 @ 85,983,232  ( 7,962,624)  -> owb after v_gemm
  char* ws = (char*)d_ws;
  unsigned short* q80    = (unsigned short*)(ws);
  unsigned short* k80    = (unsigned short*)(ws + 20971520);
  unsigned short* v_t    = (unsigned short*)(ws + 41943040);
  unsigned short* xb     = (unsigned short*)(ws + 67108864);  // also attn_o
  unsigned short* wb     = (unsigned short*)(ws + 85983232);  // wqkv, then owb

  cvt_pad<<<dim3(9112), dim3(256), 0, stream>>>(x, qw, kw, vw, xb, wb,
                                                q80, k80, v_t);
  qk_gemm<<<dim3(64, 9, 2), dim3(256), 0, stream>>>(xb, wb, qb, kb, q80, k80);
  v_gemm<<<dim3(64, 9), dim3(256), 0, stream>>>(xb, wb + 2 * (size_t)ND * ND,
                                                vb, v_t);
  attn_fwd<<<dim3(528), dim3(512), 0, stream>>>(q80, k80, v_t, xb /*= attn_o*/,
                                                ow, wb /* owb */);
  oproj_gemm<<<dim3(64, 9), dim3(256), 0, stream>>>(xb /*attn_o*/, wb, ob, out);
}

// Round 22
// 334.730 us; speedup vs baseline: 1.0043x; 1.0043x over previous
//
#include <hip/hip_runtime.h>

#define NB 2
#define NS 4096
#define ND 1152
#define NH 16
#define HD 72
#define HP 80            // q/k padded head dim (cols 72..79 zero)
#define VP 96            // v_t rows (72=ones, 73..95 zero)
// 72^-0.5 * log2(e): attention computed in exp2 domain
#define QSCALE (0.11785113019775793f * 1.4426950408889634f)

typedef float f32x4 __attribute__((ext_vector_type(4)));
typedef float f32x16 __attribute__((ext_vector_type(16)));
typedef __bf16 bf16x8 __attribute__((ext_vector_type(8)));
typedef unsigned short u16x8 __attribute__((ext_vector_type(8)));
typedef unsigned short u16x4 __attribute__((ext_vector_type(4)));
typedef unsigned int u32x4 __attribute__((ext_vector_type(4)));

__device__ __forceinline__ unsigned short f2bf(float f) {
  return __builtin_bit_cast(unsigned short, (__bf16)f);  // v_cvt RNE
}
__device__ __forceinline__ bf16x8 asbf(u16x8 u) {
  return __builtin_bit_cast(bf16x8, u);
}
__device__ __forceinline__ unsigned cvtpk(float lo, float hi) {
  unsigned d;
  asm("v_cvt_pk_bf16_f32 %0, %1, %2" : "=v"(d) : "v"(lo), "v"(hi));
  return d;
}
__device__ __forceinline__ void lane32swap(unsigned &x, unsigned &y) {
  asm volatile("v_permlane32_swap_b32 %0, %1" : "+v"(x), "+v"(y));
}
// bare hardware exp2 with COMPILER-managed VALU->TRANS hazards (R15's raw
// inline-asm version broke correctness; the builtin is the safe form).
#if __has_builtin(__builtin_amdgcn_exp2f)
#define EXP2(x) __builtin_amdgcn_exp2f(x)
#else
#define EXP2(x) exp2f(x)
#endif
// async global->LDS, 16B per lane; lds dst = wave-uniform base + lane*16
__device__ __forceinline__ void gll16(const void* g, void* l) {
  __builtin_amdgcn_global_load_lds(
      (__attribute__((address_space(1))) void*)(unsigned long long)g,
      (__attribute__((address_space(3))) void*)l, 16, 0, 0);
}

// ---------------------------------------------------------------------------
// fused pre-pass: fp32->bf16 for x + qw/kw/vw (blocks < 6552) AND pads
// (blocks >= 6552): q80/k80 cols 72..79 zero; v_t rows 72..95 (72 = ones).
// ---------------------------------------------------------------------------
__global__ __launch_bounds__(256) void cvt_pad(
    const float* __restrict__ x,
    const float* __restrict__ qw, const float* __restrict__ kw,
    const float* __restrict__ vw,
    unsigned short* __restrict__ xb, unsigned short* __restrict__ wb,
    unsigned short* __restrict__ q80, unsigned short* __restrict__ k80,
    unsigned short* __restrict__ vt) {
  if (blockIdx.x < 6552) {
    const size_t NX = (size_t)8192 * ND;      // 9437184
    const size_t NW = (size_t)ND * ND;        // 1327104
    size_t i = ((size_t)blockIdx.x * 256 + threadIdx.x) * 8;
    const float* s; unsigned short* d; size_t off;
    if (i < NX)            { s = x;  d = xb;          off = i; }
    else if (i < NX + NW)  { s = qw; d = wb;          off = i - NX; }
    else if (i < NX + 2*NW){ s = kw; d = wb + NW;     off = i - NX - NW; }
    else                   { s = vw; d = wb + 2 * NW; off = i - NX - 2 * NW; }
    f32x4 a = *(const f32x4*)(s + off);
    f32x4 b = *(const f32x4*)(s + off + 4);
    u16x8 o;
#pragma unroll
    for (int j = 0; j < 4; ++j) { o[j] = f2bf(a[j]); o[j + 4] = f2bf(b[j]); }
    *(u16x8*)(d + off) = o;
  } else {
    int i = (blockIdx.x - 6552) * 256 + threadIdx.x;
    u16x8 z = {};
    if (i < 131072) {
      *(u16x8*)(q80 + (size_t)i * HP + HD) = z;
    } else if (i < 262144) {
      *(u16x8*)(k80 + (size_t)(i - 131072) * HP + HD) = z;
    } else {
      int j = i - 262144;               // 0..393215
      int bh = j / 12288;               // 24 rows * 512 chunks per bh
      int r = j % 12288;
      int row = 72 + r / 512;
      int col = (r % 512) * 8;
      u16x8 v = z;
      if (row == HD) {
#pragma unroll
        for (int j8 = 0; j8 < 8; ++j8) v[j8] = 0x3F80;   // bf16 1.0
      }
      *(u16x8*)(vt + ((size_t)bh * VP + row) * NS + col) = v;
    }
  }
}

// ---------------------------------------------------------------------------
// Q/K projection (m97 gll structure, branchless inner loop): z picks q|k.
// C = xb . wb[z]^T + bias; 128x128 tile, BK=64, LDS [128][64] linear,
// both operands via global_load_lds width-16. Epilogue -> q80(xQSCALE)/k80.
// ---------------------------------------------------------------------------
__global__ __launch_bounds__(256) void qk_gemm(
    const unsigned short* __restrict__ xb, const unsigned short* __restrict__ wb,
    const float* __restrict__ qbias, const float* __restrict__ kbias,
    unsigned short* __restrict__ qp, unsigned short* __restrict__ kp)
{
  const int mb = blockIdx.x * 128;
  const int nb = blockIdx.y * 128;
  const int proj = blockIdx.z;
  const unsigned short* w = wb + (size_t)proj * (ND * ND);
  const float* bias = proj == 0 ? qbias : kbias;

  __shared__ __align__(16) unsigned short la[128 * 64];
  __shared__ __align__(16) unsigned short lb[128 * 64];

  const int t = threadIdx.x;
  const int lane = t & 63;
  const int wid = t >> 6;
  const int mo = (wid >> 1) * 64, no = (wid & 1) * 64;
  const int l15 = lane & 15, l4 = lane >> 4;

  const unsigned short* ga = xb + (size_t)(mb + wid * 32 + (lane >> 3)) * ND + (lane & 7) * 8;
  const unsigned short* gb = w  + (size_t)(nb + wid * 32 + (lane >> 3)) * ND + (lane & 7) * 8;

  f32x4 acc[4][4] = {};

  for (int kt = 0; kt < ND / 64; ++kt) {
    const int k0 = kt * 64;
    __syncthreads();
#pragma unroll
    for (int j = 0; j < 4; ++j) {
      gll16(ga + (size_t)j * 8 * ND + k0, &la[(wid * 4 + j) * 512]);
      gll16(gb + (size_t)j * 8 * ND + k0, &lb[(wid * 4 + j) * 512]);
    }
    __syncthreads();
#pragma unroll
    for (int ks = 0; ks < 2; ++ks) {
      bf16x8 af[4], bfr[4];
#pragma unroll
      for (int mt = 0; mt < 4; ++mt)
        af[mt] = asbf(*(const u16x8*)(&la[(mo + mt * 16 + l15) * 64 + ks * 32 + l4 * 8]));
#pragma unroll
      for (int nt = 0; nt < 4; ++nt)
        bfr[nt] = asbf(*(const u16x8*)(&lb[(no + nt * 16 + l15) * 64 + ks * 32 + l4 * 8]));
#pragma unroll
      for (int mt = 0; mt < 4; ++mt)
#pragma unroll
        for (int nt = 0; nt < 4; ++nt)
          acc[mt][nt] = __builtin_amdgcn_mfma_f32_16x16x32_bf16(af[mt], bfr[nt], acc[mt][nt], 0, 0, 0);
    }
  }

#pragma unroll
  for (int mt = 0; mt < 4; ++mt) {
#pragma unroll
    for (int nt = 0; nt < 4; ++nt) {
      const int n = nb + no + nt * 16 + l15;
      const float bval = bias[n];
      const int h = n / HD, hd = n % HD;
#pragma unroll
      for (int r = 0; r < 4; ++r) {
        const int m = mb + mo + mt * 16 + l4 * 4 + r;
        const int b = m >> 12, sl = m & (NS - 1);
        const int bh = b * NH + h;
        float v = acc[mt][nt][r] + bval;
        if (proj == 0)
          qp[((size_t)bh * NS + sl) * HP + hd] = f2bf(v * QSCALE);
        else
          kp[((size_t)bh * NS + sl) * HP + hd] = f2bf(v);
      }
    }
  }
}

// ---------------------------------------------------------------------------
// V projection (m97 gll structure, always-swapped MFMA -> C^T): v_t stores
// contiguous along s.
// ---------------------------------------------------------------------------
__global__ __launch_bounds__(256) void v_gemm(
    const unsigned short* __restrict__ xb, const unsigned short* __restrict__ wv,
    const float* __restrict__ vb, unsigned short* __restrict__ vt)
{
  const int mb = blockIdx.x * 128;
  const int nb = blockIdx.y * 128;

  __shared__ __align__(16) unsigned short la[128 * 64];
  __shared__ __align__(16) unsigned short lb[128 * 64];

  const int t = threadIdx.x;
  const int lane = t & 63;
  const int wid = t >> 6;
  const int mo = (wid >> 1) * 64, no = (wid & 1) * 64;
  const int l15 = lane & 15, l4 = lane >> 4;

  const unsigned short* ga = xb + (size_t)(mb + wid * 32 + (lane >> 3)) * ND + (lane & 7) * 8;
  const unsigned short* gb = wv + (size_t)(nb + wid * 32 + (lane >> 3)) * ND + (lane & 7) * 8;

  f32x4 acc[4][4] = {};

  for (int kt = 0; kt < ND / 64; ++kt) {
    const int k0 = kt * 64;
    __syncthreads();
#pragma unroll
    for (int j = 0; j < 4; ++j) {
      gll16(ga + (size_t)j * 8 * ND + k0, &la[(wid * 4 + j) * 512]);
      gll16(gb + (size_t)j * 8 * ND + k0, &lb[(wid * 4 + j) * 512]);
    }
    __syncthreads();
#pragma unroll
    for (int ks = 0; ks < 2; ++ks) {
      bf16x8 af[4], bfr[4];
#pragma unroll
      for (int mt = 0; mt < 4; ++mt)
        af[mt] = asbf(*(const u16x8*)(&la[(mo + mt * 16 + l15) * 64 + ks * 32 + l4 * 8]));
#pragma unroll
      for (int nt = 0; nt < 4; ++nt)
        bfr[nt] = asbf(*(const u16x8*)(&lb[(no + nt * 16 + l15) * 64 + ks * 32 + l4 * 8]));
#pragma unroll
      for (int mt = 0; mt < 4; ++mt)
#pragma unroll
        for (int nt = 0; nt < 4; ++nt)
          acc[mt][nt] = __builtin_amdgcn_mfma_f32_16x16x32_bf16(bfr[nt], af[mt], acc[mt][nt], 0, 0, 0);
    }
  }

  // acc = C^T: col(l15)=m, row(l4*4+r)=n -> stores contiguous along s
#pragma unroll
  for (int mt = 0; mt < 4; ++mt) {
    const int m = mb + mo + mt * 16 + l15;
    const int b = m >> 12, sl = m & (NS - 1);
#pragma unroll
    for (int nt = 0; nt < 4; ++nt) {
#pragma unroll
      for (int r = 0; r < 4; ++r) {
        const int n = nb + no + nt * 16 + l4 * 4 + r;
        const int h = n / HD, hd = n % HD;
        vt[(((size_t)(b * NH + h)) * VP + hd) * NS + sl] =
            f2bf(acc[mt][nt][r] + vb[n]);
      }
    }
  }
}

// ---------------------------------------------------------------------------
// exp2 + pack + PV for one 32-q group (hardware exp2 via builtin; o[3] in regs)
// ---------------------------------------------------------------------------
__device__ __forceinline__ void softmax_pv(f32x16 s, const unsigned short* cur,
                                           int mt, int lane, f32x16 o[3]) {
#pragma unroll
  for (int i = 0; i < 16; ++i) s[i] = EXP2(s[i]);
  unsigned dk[8];
#pragma unroll
  for (int r2 = 0; r2 < 4; ++r2) {
    dk[2 * r2]     = cvtpk(s[4 * r2],     s[4 * r2 + 1]);
    dk[2 * r2 + 1] = cvtpk(s[4 * r2 + 2], s[4 * r2 + 3]);
  }
#pragma unroll
  for (int a = 0; a < 2; ++a) {
    unsigned x0 = dk[4 * a + 0], y0 = dk[4 * a + 2];
    unsigned x1 = dk[4 * a + 1], y1 = dk[4 * a + 3];
    lane32swap(x0, y0);
    lane32swap(x1, y1);
    u32x4 wd = {x0, x1, y0, y1};
    bf16x8 pf = __builtin_bit_cast(bf16x8, wd);
    const int ks2 = mt * 2 + a;
    __builtin_amdgcn_s_setprio(1);
#pragma unroll
    for (int hdt = 0; hdt < 3; ++hdt) {
      bf16x8 vf = asbf(*(const u16x8*)(&cur[(640 + (hdt * 4 + ks2) * 64 + lane) * 8]));
      o[hdt] = __builtin_amdgcn_mfma_f32_32x32x16_bf16(vf, pf, o[hdt], 0, 0, 0);
    }
    __builtin_amdgcn_s_setprio(0);
  }
}

// ---------------------------------------------------------------------------
// Flash attention (R20 base + dual-chain QK interleave) + piggyback ow cvt.
// QK for BOTH k-sub-tiles computed in one interleaved loop (s0,s1 chains):
// 2x per-wave MFMA ILP so the matrix pipe accepts back-to-back issues from
// one wave instead of stalling ~32cy on each dependent MFMA (R20/R21
// counters: Mfma 55 + VALU 45 = serial sum; stagger was neutral -> test
// the per-wave dependency-stall hypothesis).
// ---------------------------------------------------------------------------
__global__ __launch_bounds__(512, 4) void attn_fwd(
    const unsigned short* __restrict__ qp,
    const unsigned short* __restrict__ kp,
    const unsigned short* __restrict__ vt,
    unsigned short* __restrict__ ao,
    const float* __restrict__ ow, unsigned short* __restrict__ owb)
{
  if (blockIdx.x >= 512) {             // o_w converter blocks
    const int tid = (blockIdx.x - 512) * 512 + threadIdx.x;  // 0..8191
    for (size_t c = tid; c < (size_t)ND * ND / 8; c += 8192) {
      size_t off = c * 8;
      f32x4 a = *(const f32x4*)(ow + off);
      f32x4 b = *(const f32x4*)(ow + off + 4);
      u16x8 o;
#pragma unroll
      for (int j = 0; j < 4; ++j) { o[j] = f2bf(a[j]); o[j + 4] = f2bf(b[j]); }
      *(u16x8*)(owb + off) = o;
    }
    return;
  }

  const int d = blockIdx.x;            // 512 attn blocks, 2 per CU
  const int qt = (d >> 3) & 15;
  const int bh = (d & 7) + 8 * (d >> 7);
  const int b = bh >> 4, h = bh & 15;
  const int qs0 = qt * 256;

  // two buffers of 1408 16B-chunks: K chunks 0..639, V chunks 640..1407
  __shared__ __align__(16) unsigned short sm[2 * 1408 * 8];

  const int t = threadIdx.x;
  const int wv = t >> 6;
  const int lane = t & 63;
  const int q = lane & 31;
  const int hh = lane >> 5;

  // Q B-frags: lane holds Q[q][ks*16 + hh*8 + j]
  bf16x8 qf[5];
  {
    const unsigned short* qrow =
        qp + ((size_t)bh * NS + qs0 + wv * 32 + q) * HP + hh * 8;
#pragma unroll
    for (int ks = 0; ks < 5; ++ks)
      qf[ks] = asbf(*(const u16x8*)(qrow + ks * 16));
  }

  // staging: 22 chunk-groups of 64; wave wv handles g = wv, wv+8, wv+16(wv<6).
  // g<10: K group (mt=g/5, ks=g%5); g>=10: V group f=g-10 (hdt=f>>2, ks2=f&3).
  const unsigned short* kb0 = kp + (size_t)bh * NS * HP;
  const unsigned short* vb0 = vt + (size_t)bh * VP * NS;
  const unsigned short* gp[3];
  int stp[3], goff[3];
  const bool has2 = wv < 6;
#pragma unroll
  for (int j = 0; j < 3; ++j) {
    int g = wv + 8 * j;
    if (g > 21) g = 21;                // inert clamp for waves 6,7 j=2
    if (g < 10) {
      gp[j] = kb0 + ((g / 5) * 32 + (lane & 31)) * HP + (g % 5) * 16 + (lane >> 5) * 8;
      stp[j] = 64 * HP;
    } else {
      const int f = g - 10;
      gp[j] = vb0 + (size_t)((f >> 2) * 32 + (lane & 31)) * NS + (f & 3) * 16 + (lane >> 5) * 8;
      stp[j] = 64;
    }
    goff[j] = g * 512;
  }

  f32x16 o[3] = {};   // O^T: col q, row hd = hdt*32+(reg&3)+8*(reg>>2)+4*hh

  // prologue: stage tile 0 into buffer 0
  gll16(gp[0], sm + goff[0]); gp[0] += stp[0];
  gll16(gp[1], sm + goff[1]); gp[1] += stp[1];
  if (has2) { gll16(gp[2], sm + goff[2]); gp[2] += stp[2]; }
  __syncthreads();

  for (int it = 0; it < NS / 64; ++it) {
    unsigned short* cur = sm + (it & 1) * 11264;
    unsigned short* nxt = sm + ((it + 1) & 1) * 11264;
    if (it < NS / 64 - 1) {            // issue next tile; drains at the barrier
      gll16(gp[0], nxt + goff[0]); gp[0] += stp[0];
      gll16(gp[1], nxt + goff[1]); gp[1] += stp[1];
      if (has2) { gll16(gp[2], nxt + goff[2]); gp[2] += stp[2]; }
    }

    // S^T tiles [32k x 32q] for both sub-tiles, two independent MFMA chains
    f32x16 s0 = {}, s1 = {};
    __builtin_amdgcn_s_setprio(1);
#pragma unroll
    for (int ks = 0; ks < 5; ++ks) {
      bf16x8 kf0 = asbf(*(const u16x8*)(&cur[(ks * 64 + lane) * 8]));
      bf16x8 kf1 = asbf(*(const u16x8*)(&cur[((5 + ks) * 64 + lane) * 8]));
      s0 = __builtin_amdgcn_mfma_f32_32x32x16_bf16(kf0, qf[ks], s0, 0, 0, 0);
      s1 = __builtin_amdgcn_mfma_f32_32x32x16_bf16(kf1, qf[ks], s1, 0, 0, 0);
    }
    __builtin_amdgcn_s_setprio(0);
    softmax_pv(s0, cur, 0, lane, o);
    softmax_pv(s1, cur, 1, lane, o);

    __syncthreads();                   // drains gll(t+1); all waves done w/ cur
  }

  // epilogue: denom = O row 72 (o[2] reg 4, hh=0 lanes)
  const float l_tot = __shfl(o[2][4], q);
  const float inv = 1.0f / l_tot;
  const int srow = qs0 + wv * 32 + q;
  unsigned short* ob = ao + ((size_t)b * NS + srow) * ND + h * HD;
#pragma unroll
  for (int hdt = 0; hdt < 3; ++hdt)
#pragma unroll
    for (int r2 = 0; r2 < 4; ++r2) {
      const int hd0 = hdt * 32 + r2 * 8 + hh * 4;
      if (hd0 < HD) {
        u16x4 ov;
#pragma unroll
        for (int r0 = 0; r0 < 4; ++r0) ov[r0] = f2bf(o[hdt][r2 * 4 + r0] * inv);
        *(u16x4*)(ob + hd0) = ov;
      }
    }
}

// ---------------------------------------------------------------------------
// O projection (qk_gemm gll structure, both operands bf16):
// out[8192,1152] fp32 = attn_o(bf16) . ow_bf16^T + o_b
// ---------------------------------------------------------------------------
__global__ __launch_bounds__(256) void oproj_gemm(
    const unsigned short* __restrict__ a,
    const unsigned short* __restrict__ wbf, const float* __restrict__ bias,
    float* __restrict__ out)
{
  const int mb = blockIdx.x * 128;
  const int nb = blockIdx.y * 128;

  __shared__ __align__(16) unsigned short la[128 * 64];
  __shared__ __align__(16) unsigned short lb[128 * 64];

  const int t = threadIdx.x;
  const int lane = t & 63;
  const int wid = t >> 6;
  const int mo = (wid >> 1) * 64, no = (wid & 1) * 64;
  const int l15 = lane & 15, l4 = lane >> 4;

  const unsigned short* ga = a   + (size_t)(mb + wid * 32 + (lane >> 3)) * ND + (lane & 7) * 8;
  const unsigned short* gb = wbf + (size_t)(nb + wid * 32 + (lane >> 3)) * ND + (lane & 7) * 8;

  f32x4 acc[4][4] = {};

  for (int kt = 0; kt < ND / 64; ++kt) {
    const int k0 = kt * 64;
    __syncthreads();
#pragma unroll
    for (int j = 0; j < 4; ++j) {
      gll16(ga + (size_t)j * 8 * ND + k0, &la[(wid * 4 + j) * 512]);
      gll16(gb + (size_t)j * 8 * ND + k0, &lb[(wid * 4 + j) * 512]);
    }
    __syncthreads();
#pragma unroll
    for (int ks = 0; ks < 2; ++ks) {
      bf16x8 af[4], bfr[4];
#pragma unroll
      for (int mt = 0; mt < 4; ++mt)
        af[mt] = asbf(*(const u16x8*)(&la[(mo + mt * 16 + l15) * 64 + ks * 32 + l4 * 8]));
#pragma unroll
      for (int nt = 0; nt < 4; ++nt)
        bfr[nt] = asbf(*(const u16x8*)(&lb[(no + nt * 16 + l15) * 64 + ks * 32 + l4 * 8]));
#pragma unroll
      for (int mt = 0; mt < 4; ++mt)
#pragma unroll
        for (int nt = 0; nt < 4; ++nt)
          acc[mt][nt] = __builtin_amdgcn_mfma_f32_16x16x32_bf16(af[mt], bfr[nt], acc[mt][nt], 0, 0, 0);
    }
  }

#pragma unroll
  for (int mt = 0; mt < 4; ++mt)
#pragma unroll
    for (int nt = 0; nt < 4; ++nt) {
      const int n = nb + no + nt * 16 + l15;
      const float bval = bias[n];
#pragma unroll
      for (int r = 0; r < 4; ++r) {
        const int m = mb + mo + mt * 16 + l4 * 4 + r;
        out[(size_t)m * ND + n] = acc[mt][nt][r] + bval;
      }
    }
}

// ---------------------------------------------------------------------------
extern "C" void kernel_launch(void* const* d_in, const int* in_sizes, int n_in,
                              void* d_out, int out_size, void* d_ws, size_t ws_size,
                              hipStream_t stream) {
  const float* x  = (const float*)d_in[0];
  const float* qw = (const float*)d_in[1];
  const float* qb = (const float*)d_in[2];
  const float* kw = (const float*)d_in[3];
  const float* kb = (const float*)d_in[4];
  const float* vw = (const float*)d_in[5];
  const float* vb = (const float*)d_in[6];
  const float* ow = (const float*)d_in[7];
  const float* ob = (const float*)d_in[8];
  float* out = (float*)d_out;

  // ws layout (bytes), total 93,945,856 (== R7's proven footprint):
  //   q80    [2,16,4096,80] bf16 @ 0           (20,971,520)
  //   k80    [2,16,4096,80] bf16 @ 20,971,520  (20,971,520)
  //   v_t    [2,16,96,4096] bf16 @ 41,943,040  (25,165,824)
  //   xb/ao  [8192,1152]    bf16 @ 67,108,864  (18,874,368)  xb dies before ao
  //   wqkv   3x[1152,1152]  bf16 @ 85,983,232  ( 7,962,624)  -> owb after v_gemm
  char* ws = (char*)d_ws;
  unsigned short* q80    = (unsigned short*)(ws);
  unsigned short* k80    = (unsigned short*)(ws + 20971520);
  unsigned short* v_t    = (unsigned short*)(ws + 41943040);
  unsigned short* xb     = (unsigned short*)(ws + 67108864);  // also attn_o
  unsigned short* wb     = (unsigned short*)(ws + 85983232);  // wqkv, then owb

  cvt_pad<<<dim3(9112), dim3(256), 0, stream>>>(x, qw, kw, vw, xb, wb,
                                                q80, k80, v_t);
  qk_gemm<<<dim3(64, 9, 2), dim3(256), 0, stream>>>(xb, wb, qb, kb, q80, k80);
  v_gemm<<<dim3(64, 9), dim3(256), 0, stream>>>(xb, wb + 2 * (size_t)ND * ND,
                                                vb, v_t);
  attn_fwd<<<dim3(528), dim3(512), 0, stream>>>(q80, k80, v_t, xb /*= attn_o*/,
                                                ow, wb /* owb */);
  oproj_gemm<<<dim3(64, 9), dim3(256), 0, stream>>>(xb /*attn_o*/, wb, ob, out);
}

// Round 23
// 331.381 us; speedup vs baseline: 1.0144x; 1.0101x over previous
//
#include <hip/hip_runtime.h>

#define NB 2
#define NS 4096
#define ND 1152
#define NH 16
#define HD 72
#define HP 80            // q/k padded head dim (cols 72..79 zero)
#define VP 96            // v_t rows (72=ones, 73..95 zero)
// 72^-0.5 * log2(e): attention computed in exp2 domain
#define QSCALE (0.11785113019775793f * 1.4426950408889634f)

typedef float f32x4 __attribute__((ext_vector_type(4)));
typedef float f32x16 __attribute__((ext_vector_type(16)));
typedef __bf16 bf16x8 __attribute__((ext_vector_type(8)));
typedef unsigned short u16x8 __attribute__((ext_vector_type(8)));
typedef unsigned short u16x4 __attribute__((ext_vector_type(4)));
typedef unsigned int u32x4 __attribute__((ext_vector_type(4)));

__device__ __forceinline__ unsigned short f2bf(float f) {
  return __builtin_bit_cast(unsigned short, (__bf16)f);  // v_cvt RNE
}
__device__ __forceinline__ bf16x8 asbf(u16x8 u) {
  return __builtin_bit_cast(bf16x8, u);
}
__device__ __forceinline__ unsigned cvtpk(float lo, float hi) {
  unsigned d;
  asm("v_cvt_pk_bf16_f32 %0, %1, %2" : "=v"(d) : "v"(lo), "v"(hi));
  return d;
}
__device__ __forceinline__ void lane32swap(unsigned &x, unsigned &y) {
  asm volatile("v_permlane32_swap_b32 %0, %1" : "+v"(x), "+v"(y));
}
// bare hardware exp2 with COMPILER-managed VALU->TRANS hazards (R15's raw
// inline-asm version broke correctness; the builtin is the safe form).
#if __has_builtin(__builtin_amdgcn_exp2f)
#define EXP2(x) __builtin_amdgcn_exp2f(x)
#else
#define EXP2(x) exp2f(x)
#endif
// async global->LDS, 16B per lane; lds dst = wave-uniform base + lane*16
__device__ __forceinline__ void gll16(const void* g, void* l) {
  __builtin_amdgcn_global_load_lds(
      (__attribute__((address_space(1))) void*)(unsigned long long)g,
      (__attribute__((address_space(3))) void*)l, 16, 0, 0);
}

// ---------------------------------------------------------------------------
// fused pre-pass: fp32->bf16 for x + qw/kw/vw (blocks < 6552) AND pads
// (blocks >= 6552): q80/k80 cols 72..79 zero; v_t rows 72..95 (72 = ones).
// ---------------------------------------------------------------------------
__global__ __launch_bounds__(256) void cvt_pad(
    const float* __restrict__ x,
    const float* __restrict__ qw, const float* __restrict__ kw,
    const float* __restrict__ vw,
    unsigned short* __restrict__ xb, unsigned short* __restrict__ wb,
    unsigned short* __restrict__ q80, unsigned short* __restrict__ k80,
    unsigned short* __restrict__ vt) {
  if (blockIdx.x < 6552) {
    const size_t NX = (size_t)8192 * ND;      // 9437184
    const size_t NW = (size_t)ND * ND;        // 1327104
    size_t i = ((size_t)blockIdx.x * 256 + threadIdx.x) * 8;
    const float* s; unsigned short* d; size_t off;
    if (i < NX)            { s = x;  d = xb;          off = i; }
    else if (i < NX + NW)  { s = qw; d = wb;          off = i - NX; }
    else if (i < NX + 2*NW){ s = kw; d = wb + NW;     off = i - NX - NW; }
    else                   { s = vw; d = wb + 2 * NW; off = i - NX - 2 * NW; }
    f32x4 a = *(const f32x4*)(s + off);
    f32x4 b = *(const f32x4*)(s + off + 4);
    u16x8 o;
#pragma unroll
    for (int j = 0; j < 4; ++j) { o[j] = f2bf(a[j]); o[j + 4] = f2bf(b[j]); }
    *(u16x8*)(d + off) = o;
  } else {
    int i = (blockIdx.x - 6552) * 256 + threadIdx.x;
    u16x8 z = {};
    if (i < 131072) {
      *(u16x8*)(q80 + (size_t)i * HP + HD) = z;
    } else if (i < 262144) {
      *(u16x8*)(k80 + (size_t)(i - 131072) * HP + HD) = z;
    } else {
      int j = i - 262144;               // 0..393215
      int bh = j / 12288;               // 24 rows * 512 chunks per bh
      int r = j % 12288;
      int row = 72 + r / 512;
      int col = (r % 512) * 8;
      u16x8 v = z;
      if (row == HD) {
#pragma unroll
        for (int j8 = 0; j8 < 8; ++j8) v[j8] = 0x3F80;   // bf16 1.0
      }
      *(u16x8*)(vt + ((size_t)bh * VP + row) * NS + col) = v;
    }
  }
}

// ---------------------------------------------------------------------------
// Merged Q/K/V projection, one launch (z = 0:q, 1:k, 2:v). Whole-kernel
// block-uniform branch selects between two complete, internally branchless
// bodies (R12 lesson: never branch inside the unrolled MFMA loop).
// Both paths: m97 gll structure, 128x128 tile, BK=64, LDS [128][64] linear.
//   q/k path: normal MFMA -> q80 (x QSCALE) / k80.
//   v path:   swapped MFMA -> C^T -> v_t stores contiguous along s.
// ---------------------------------------------------------------------------
__global__ __launch_bounds__(256) void qkv_gemm(
    const unsigned short* __restrict__ xb, const unsigned short* __restrict__ wb,
    const float* __restrict__ qbias, const float* __restrict__ kbias,
    const float* __restrict__ vbias,
    unsigned short* __restrict__ qp, unsigned short* __restrict__ kp,
    unsigned short* __restrict__ vt)
{
  const int mb = blockIdx.x * 128;
  const int nb = blockIdx.y * 128;
  const int proj = blockIdx.z;
  const unsigned short* w = wb + (size_t)proj * (ND * ND);

  __shared__ __align__(16) unsigned short la[128 * 64];
  __shared__ __align__(16) unsigned short lb[128 * 64];

  const int t = threadIdx.x;
  const int lane = t & 63;
  const int wid = t >> 6;
  const int mo = (wid >> 1) * 64, no = (wid & 1) * 64;
  const int l15 = lane & 15, l4 = lane >> 4;

  const unsigned short* ga = xb + (size_t)(mb + wid * 32 + (lane >> 3)) * ND + (lane & 7) * 8;
  const unsigned short* gb = w  + (size_t)(nb + wid * 32 + (lane >> 3)) * ND + (lane & 7) * 8;

  f32x4 acc[4][4] = {};

  if (proj < 2) {
    const float* bias = proj == 0 ? qbias : kbias;
    for (int kt = 0; kt < ND / 64; ++kt) {
      const int k0 = kt * 64;
      __syncthreads();
#pragma unroll
      for (int j = 0; j < 4; ++j) {
        gll16(ga + (size_t)j * 8 * ND + k0, &la[(wid * 4 + j) * 512]);
        gll16(gb + (size_t)j * 8 * ND + k0, &lb[(wid * 4 + j) * 512]);
      }
      __syncthreads();
#pragma unroll
      for (int ks = 0; ks < 2; ++ks) {
        bf16x8 af[4], bfr[4];
#pragma unroll
        for (int mt = 0; mt < 4; ++mt)
          af[mt] = asbf(*(const u16x8*)(&la[(mo + mt * 16 + l15) * 64 + ks * 32 + l4 * 8]));
#pragma unroll
        for (int nt = 0; nt < 4; ++nt)
          bfr[nt] = asbf(*(const u16x8*)(&lb[(no + nt * 16 + l15) * 64 + ks * 32 + l4 * 8]));
#pragma unroll
        for (int mt = 0; mt < 4; ++mt)
#pragma unroll
          for (int nt = 0; nt < 4; ++nt)
            acc[mt][nt] = __builtin_amdgcn_mfma_f32_16x16x32_bf16(af[mt], bfr[nt], acc[mt][nt], 0, 0, 0);
      }
    }

#pragma unroll
    for (int mt = 0; mt < 4; ++mt) {
#pragma unroll
      for (int nt = 0; nt < 4; ++nt) {
        const int n = nb + no + nt * 16 + l15;
        const float bval = bias[n];
        const int h = n / HD, hd = n % HD;
#pragma unroll
        for (int r = 0; r < 4; ++r) {
          const int m = mb + mo + mt * 16 + l4 * 4 + r;
          const int b = m >> 12, sl = m & (NS - 1);
          const int bh = b * NH + h;
          float v = acc[mt][nt][r] + bval;
          if (proj == 0)
            qp[((size_t)bh * NS + sl) * HP + hd] = f2bf(v * QSCALE);
          else
            kp[((size_t)bh * NS + sl) * HP + hd] = f2bf(v);
        }
      }
    }
  } else {
    for (int kt = 0; kt < ND / 64; ++kt) {
      const int k0 = kt * 64;
      __syncthreads();
#pragma unroll
      for (int j = 0; j < 4; ++j) {
        gll16(ga + (size_t)j * 8 * ND + k0, &la[(wid * 4 + j) * 512]);
        gll16(gb + (size_t)j * 8 * ND + k0, &lb[(wid * 4 + j) * 512]);
      }
      __syncthreads();
#pragma unroll
      for (int ks = 0; ks < 2; ++ks) {
        bf16x8 af[4], bfr[4];
#pragma unroll
        for (int mt = 0; mt < 4; ++mt)
          af[mt] = asbf(*(const u16x8*)(&la[(mo + mt * 16 + l15) * 64 + ks * 32 + l4 * 8]));
#pragma unroll
        for (int nt = 0; nt < 4; ++nt)
          bfr[nt] = asbf(*(const u16x8*)(&lb[(no + nt * 16 + l15) * 64 + ks * 32 + l4 * 8]));
#pragma unroll
        for (int mt = 0; mt < 4; ++mt)
#pragma unroll
          for (int nt = 0; nt < 4; ++nt)
            acc[mt][nt] = __builtin_amdgcn_mfma_f32_16x16x32_bf16(bfr[nt], af[mt], acc[mt][nt], 0, 0, 0);
      }
    }

    // acc = C^T: col(l15)=m, row(l4*4+r)=n -> stores contiguous along s
#pragma unroll
    for (int mt = 0; mt < 4; ++mt) {
      const int m = mb + mo + mt * 16 + l15;
      const int b = m >> 12, sl = m & (NS - 1);
#pragma unroll
      for (int nt = 0; nt < 4; ++nt) {
#pragma unroll
        for (int r = 0; r < 4; ++r) {
          const int n = nb + no + nt * 16 + l4 * 4 + r;
          const int h = n / HD, hd = n % HD;
          vt[(((size_t)(b * NH + h)) * VP + hd) * NS + sl] =
              f2bf(acc[mt][nt][r] + vbias[n]);
        }
      }
    }
  }
}

// ---------------------------------------------------------------------------
// exp2 + pack + PV for one 32-q group (hardware exp2 via builtin; o[3] in regs)
// ---------------------------------------------------------------------------
__device__ __forceinline__ void softmax_pv(f32x16 s, const unsigned short* cur,
                                           int mt, int lane, f32x16 o[3]) {
#pragma unroll
  for (int i = 0; i < 16; ++i) s[i] = EXP2(s[i]);
  unsigned dk[8];
#pragma unroll
  for (int r2 = 0; r2 < 4; ++r2) {
    dk[2 * r2]     = cvtpk(s[4 * r2],     s[4 * r2 + 1]);
    dk[2 * r2 + 1] = cvtpk(s[4 * r2 + 2], s[4 * r2 + 3]);
  }
#pragma unroll
  for (int a = 0; a < 2; ++a) {
    unsigned x0 = dk[4 * a + 0], y0 = dk[4 * a + 2];
    unsigned x1 = dk[4 * a + 1], y1 = dk[4 * a + 3];
    lane32swap(x0, y0);
    lane32swap(x1, y1);
    u32x4 wd = {x0, x1, y0, y1};
    bf16x8 pf = __builtin_bit_cast(bf16x8, wd);
    const int ks2 = mt * 2 + a;
    __builtin_amdgcn_s_setprio(1);
#pragma unroll
    for (int hdt = 0; hdt < 3; ++hdt) {
      bf16x8 vf = asbf(*(const u16x8*)(&cur[(640 + (hdt * 4 + ks2) * 64 + lane) * 8]));
      o[hdt] = __builtin_amdgcn_mfma_f32_32x32x16_bf16(vf, pf, o[hdt], 0, 0, 0);
    }
    __builtin_amdgcn_s_setprio(0);
  }
}

// ---------------------------------------------------------------------------
// Flash attention (R20 form: 166-168 us measured best) + piggyback ow cvt.
// 32x32x16 MFMA, 8 waves x 32 q = 256 q/block, grid 512 = 2 blocks/CU.
// Double-buffered LDS + gll, one barrier/iter; in-register P; m=0 softmax;
// V-ones denominator; setprio. (R21 stagger and R22 dual-chain both neutral.)
// ---------------------------------------------------------------------------
__global__ __launch_bounds__(512, 4) void attn_fwd(
    const unsigned short* __restrict__ qp,
    const unsigned short* __restrict__ kp,
    const unsigned short* __restrict__ vt,
    unsigned short* __restrict__ ao,
    const float* __restrict__ ow, unsigned short* __restrict__ owb)
{
  if (blockIdx.x >= 512) {             // o_w converter blocks
    const int tid = (blockIdx.x - 512) * 512 + threadIdx.x;  // 0..8191
    for (size_t c = tid; c < (size_t)ND * ND / 8; c += 8192) {
      size_t off = c * 8;
      f32x4 a = *(const f32x4*)(ow + off);
      f32x4 b = *(const f32x4*)(ow + off + 4);
      u16x8 o;
#pragma unroll
      for (int j = 0; j < 4; ++j) { o[j] = f2bf(a[j]); o[j + 4] = f2bf(b[j]); }
      *(u16x8*)(owb + off) = o;
    }
    return;
  }

  const int d = blockIdx.x;            // 512 attn blocks, 2 per CU
  const int qt = (d >> 3) & 15;
  const int bh = (d & 7) + 8 * (d >> 7);
  const int b = bh >> 4, h = bh & 15;
  const int qs0 = qt * 256;

  // two buffers of 1408 16B-chunks: K chunks 0..639, V chunks 640..1407
  __shared__ __align__(16) unsigned short sm[2 * 1408 * 8];

  const int t = threadIdx.x;
  const int wv = t >> 6;
  const int lane = t & 63;
  const int q = lane & 31;
  const int hh = lane >> 5;

  // Q B-frags: lane holds Q[q][ks*16 + hh*8 + j]
  bf16x8 qf[5];
  {
    const unsigned short* qrow =
        qp + ((size_t)bh * NS + qs0 + wv * 32 + q) * HP + hh * 8;
#pragma unroll
    for (int ks = 0; ks < 5; ++ks)
      qf[ks] = asbf(*(const u16x8*)(qrow + ks * 16));
  }

  // staging: 22 chunk-groups of 64; wave wv handles g = wv, wv+8, wv+16(wv<6).
  // g<10: K group (mt=g/5, ks=g%5); g>=10: V group f=g-10 (hdt=f>>2, ks2=f&3).
  const unsigned short* kb0 = kp + (size_t)bh * NS * HP;
  const unsigned short* vb0 = vt + (size_t)bh * VP * NS;
  const unsigned short* gp[3];
  int stp[3], goff[3];
  const bool has2 = wv < 6;
#pragma unroll
  for (int j = 0; j < 3; ++j) {
    int g = wv + 8 * j;
    if (g > 21) g = 21;                // inert clamp for waves 6,7 j=2
    if (g < 10) {
      gp[j] = kb0 + ((g / 5) * 32 + (lane & 31)) * HP + (g % 5) * 16 + (lane >> 5) * 8;
      stp[j] = 64 * HP;
    } else {
      const int f = g - 10;
      gp[j] = vb0 + (size_t)((f >> 2) * 32 + (lane & 31)) * NS + (f & 3) * 16 + (lane >> 5) * 8;
      stp[j] = 64;
    }
    goff[j] = g * 512;
  }

  f32x16 o[3] = {};   // O^T: col q, row hd = hdt*32+(reg&3)+8*(reg>>2)+4*hh

  // prologue: stage tile 0 into buffer 0
  gll16(gp[0], sm + goff[0]); gp[0] += stp[0];
  gll16(gp[1], sm + goff[1]); gp[1] += stp[1];
  if (has2) { gll16(gp[2], sm + goff[2]); gp[2] += stp[2]; }
  __syncthreads();

  for (int it = 0; it < NS / 64; ++it) {
    unsigned short* cur = sm + (it & 1) * 11264;
    unsigned short* nxt = sm + ((it + 1) & 1) * 11264;
    if (it < NS / 64 - 1) {            // issue next tile; drains at the barrier
      gll16(gp[0], nxt + goff[0]); gp[0] += stp[0];
      gll16(gp[1], nxt + goff[1]); gp[1] += stp[1];
      if (has2) { gll16(gp[2], nxt + goff[2]); gp[2] += stp[2]; }
    }

#pragma unroll
    for (int mt = 0; mt < 2; ++mt) {
      // S^T tile [32k x 32q], contraction over hd 0..79
      f32x16 s = {};
      __builtin_amdgcn_s_setprio(1);
#pragma unroll
      for (int ks = 0; ks < 5; ++ks) {
        bf16x8 kf = asbf(*(const u16x8*)(&cur[((mt * 5 + ks) * 64 + lane) * 8]));
        s = __builtin_amdgcn_mfma_f32_32x32x16_bf16(kf, qf[ks], s, 0, 0, 0);
      }
      __builtin_amdgcn_s_setprio(0);
      softmax_pv(s, cur, mt, lane, o);
    }
    __syncthreads();                   // drains gll(t+1); all waves done w/ cur
  }

  // epilogue: denom = O row 72 (o[2] reg 4, hh=0 lanes)
  const float l_tot = __shfl(o[2][4], q);
  const float inv = 1.0f / l_tot;
  const int srow = qs0 + wv * 32 + q;
  unsigned short* ob = ao + ((size_t)b * NS + srow) * ND + h * HD;
#pragma unroll
  for (int hdt = 0; hdt < 3; ++hdt)
#pragma unroll
    for (int r2 = 0; r2 < 4; ++r2) {
      const int hd0 = hdt * 32 + r2 * 8 + hh * 4;
      if (hd0 < HD) {
        u16x4 ov;
#pragma unroll
        for (int r0 = 0; r0 < 4; ++r0) ov[r0] = f2bf(o[hdt][r2 * 4 + r0] * inv);
        *(u16x4*)(ob + hd0) = ov;
      }
    }
}

// ---------------------------------------------------------------------------
// O projection (qk_gemm gll structure, both operands bf16):
// out[8192,1152] fp32 = attn_o(bf16) . ow_bf16^T + o_b
// ---------------------------------------------------------------------------
__global__ __launch_bounds__(256) void oproj_gemm(
    const unsigned short* __restrict__ a,
    const unsigned short* __restrict__ wbf, const float* __restrict__ bias,
    float* __restrict__ out)
{
  const int mb = blockIdx.x * 128;
  const int nb = blockIdx.y * 128;

  __shared__ __align__(16) unsigned short la[128 * 64];
  __shared__ __align__(16) unsigned short lb[128 * 64];

  const int t = threadIdx.x;
  const int lane = t & 63;
  const int wid = t >> 6;
  const int mo = (wid >> 1) * 64, no = (wid & 1) * 64;
  const int l15 = lane & 15, l4 = lane >> 4;

  const unsigned short* ga = a   + (size_t)(mb + wid * 32 + (lane >> 3)) * ND + (lane & 7) * 8;
  const unsigned short* gb = wbf + (size_t)(nb + wid * 32 + (lane >> 3)) * ND + (lane & 7) * 8;

  f32x4 acc[4][4] = {};

  for (int kt = 0; kt < ND / 64; ++kt) {
    const int k0 = kt * 64;
    __syncthreads();
#pragma unroll
    for (int j = 0; j < 4; ++j) {
      gll16(ga + (size_t)j * 8 * ND + k0, &la[(wid * 4 + j) * 512]);
      gll16(gb + (size_t)j * 8 * ND + k0, &lb[(wid * 4 + j) * 512]);
    }
    __syncthreads();
#pragma unroll
    for (int ks = 0; ks < 2; ++ks) {
      bf16x8 af[4], bfr[4];
#pragma unroll
      for (int mt = 0; mt < 4; ++mt)
        af[mt] = asbf(*(const u16x8*)(&la[(mo + mt * 16 + l15) * 64 + ks * 32 + l4 * 8]));
#pragma unroll
      for (int nt = 0; nt < 4; ++nt)
        bfr[nt] = asbf(*(const u16x8*)(&lb[(no + nt * 16 + l15) * 64 + ks * 32 + l4 * 8]));
#pragma unroll
      for (int mt = 0; mt < 4; ++mt)
#pragma unroll
        for (int nt = 0; nt < 4; ++nt)
          acc[mt][nt] = __builtin_amdgcn_mfma_f32_16x16x32_bf16(af[mt], bfr[nt], acc[mt][nt], 0, 0, 0);
    }
  }

#pragma unroll
  for (int mt = 0; mt < 4; ++mt)
#pragma unroll
    for (int nt = 0; nt < 4; ++nt) {
      const int n = nb + no + nt * 16 + l15;
      const float bval = bias[n];
#pragma unroll
      for (int r = 0; r < 4; ++r) {
        const int m = mb + mo + mt * 16 + l4 * 4 + r;
        out[(size_t)m * ND + n] = acc[mt][nt][r] + bval;
      }
    }
}

// ---------------------------------------------------------------------------
extern "C" void kernel_launch(void* const* d_in, const int* in_sizes, int n_in,
                              void* d_out, int out_size, void* d_ws, size_t ws_size,
                              hipStream_t stream) {
  const float* x  = (const float*)d_in[0];
  const float* qw = (const float*)d_in[1];
  const float* qb = (const float*)d_in[2];
  const float* kw = (const float*)d_in[3];
  const float* kb = (const float*)d_in[4];
  const float* vw = (const float*)d_in[5];
  const float* vb = (const float*)d_in[6];
  const float* ow = (const float*)d_in[7];
  const float* ob = (const float*)d_in[8];
  float* out = (float*)d_out;

  // ws layout (bytes), total 93,945,856 (== R7's proven footprint):
  //   q80    [2,16,4096,80] bf16 @ 0           (20,971,520)
  //   k80    [2,16,4096,80] bf16 @ 20,971,520  (20,971,520)
  //   v_t    [2,16,96,4096] bf16 @ 41,943,040  (25,165,824)
  //   xb/ao  [8192,1152]    bf16 @ 67,108,864  (18,874,368)  xb dies before ao
  //   wqkv   3x[1152,1152]  bf16 @ 85,983,232  ( 7,962,624)  -> owb after qkv
  char* ws = (char*)d_ws;
  unsigned short* q80    = (unsigned short*)(ws);
  unsigned short* k80    = (unsigned short*)(ws + 20971520);
  unsigned short* v_t    = (unsigned short*)(ws + 41943040);
  unsigned short* xb     = (unsigned short*)(ws + 67108864);  // also attn_o
  unsigned short* wb     = (unsigned short*)(ws + 85983232);  // wqkv, then owb

  cvt_pad<<<dim3(9112), dim3(256), 0, stream>>>(x, qw, kw, vw, xb, wb,
                                                q80, k80, v_t);
  qkv_gemm<<<dim3(64, 9, 3), dim3(256), 0, stream>>>(xb, wb, qb, kb, vb,
                                                     q80, k80, v_t);
  attn_fwd<<<dim3(528), dim3(512), 0, stream>>>(q80, k80, v_t, xb /*= attn_o*/,
                                                ow, wb /* owb */);
  oproj_gemm<<<dim3(64, 9), dim3(256), 0, stream>>>(xb /*attn_o*/, wb, ob, out);
}